// Round 5
// baseline (468.820 us; speedup 1.0000x reference)
//
#include <hip/hip_runtime.h>
#include <hip/hip_cooperative_groups.h>
#include <math.h>

namespace cg = cooperative_groups;

#define NB 16
#define NN 24
#define NA 384       /* atoms total */
#define FF 128
#define CC 27
#define MAXNBR 32    /* physically <= 23 possible (image spacing L > 2r) */
#define NBLK 256
#define NTHR 256

// ---- static device scratch (d_ws unused; everything read is rewritten every call) ----
__device__ int   g_cnt[NA];
__device__ float g_radius[NB];
__device__ float g_sigma[4];
__device__ int   g_nj[NA*MAXNBR];
__device__ float g_nd[NA*MAXNBR];
__device__ float g_nw[NA*MAXNBR];
__device__ float g_featA[NA*FF];
__device__ float g_featB[NA*FF];
__device__ float g_proj[NA*4*FF];   // per atom: gi, gj, si, sj

__device__ __forceinline__ float softplusf(float x){ return fmaxf(x,0.f) + log1pf(expf(-fabsf(x))); }
__device__ __forceinline__ float sigmoidf(float x){ return 1.f/(1.f+expf(-x)); }

__global__ void __launch_bounds__(NTHR)
k_mega(const float* __restrict__ pos,  const float* __restrict__ cell,
       const float* __restrict__ emb,
       const float* __restrict__ conv_Wf, const float* __restrict__ conv_bf,
       const float* __restrict__ conv_Ws, const float* __restrict__ conv_bs,
       const float* __restrict__ fc_W,  const float* __restrict__ fc_b,
       const float* __restrict__ W_out, const float* __restrict__ b_out,
       const int* __restrict__ z,       float* __restrict__ out)
{
  cg::grid_group grid = cg::this_grid();
  const int bid = blockIdx.x, tid = threadIdx.x;

  __shared__ float s_w[FF*129];        // sigma: W cached, stride 129 (conflict-free)
  __shared__ float s_ft[2][FF];        // proj: two concurrent feature vectors
  __shared__ float s_u[FF], s_v[FF], s_red[FF];

  // ================= S0: sigma (blocks 0-2) | init (blocks 3+) =================
  if (bid < 3) {
    const float* W = fc_W + bid*FF*FF;
    for (int idx = tid; idx < FF*FF; idx += NTHR) {
      int r = idx >> 7, c = idx & 127;
      s_w[r*129+c] = W[idx];           // coalesced global read
    }
    if (tid < FF) s_u[tid] = 0.08838834764831845f;  // 1/sqrt(128): ones/||ones||
    __syncthreads();
    for (int it = 0; it < 5; it++) {
      if (tid < FF) {                  // v = W u
        float s = 0.f;
        #pragma unroll 8
        for (int c=0;c<FF;c++) s += s_w[tid*129+c]*s_u[c];
        s_v[tid] = s; s_red[tid] = s*s;
      }
      __syncthreads();
      for (int st=64; st>0; st>>=1){ if (tid<st) s_red[tid]+=s_red[tid+st]; __syncthreads(); }
      float nv = sqrtf(s_red[0]) + 1e-12f;
      __syncthreads();
      if (tid < FF) s_v[tid] /= nv;
      __syncthreads();
      if (tid < FF) {                  // u = W^T v
        float s = 0.f;
        #pragma unroll 8
        for (int r=0;r<FF;r++) s += s_w[r*129+tid]*s_v[r];
        s_u[tid] = s; s_red[tid] = s*s;
      }
      __syncthreads();
      for (int st=64; st>0; st>>=1){ if (tid<st) s_red[tid]+=s_red[tid+st]; __syncthreads(); }
      float nu = sqrtf(s_red[0]) + 1e-12f;
      __syncthreads();
      if (tid < FF) s_u[tid] /= nu;
      __syncthreads();
    }
    if (tid < FF) {                    // sigma = v . (W u)
      float s = 0.f;
      #pragma unroll 8
      for (int c=0;c<FF;c++) s += s_w[tid*129+c]*s_u[c];
      s_red[tid] = s_v[tid]*s;
    }
    __syncthreads();
    for (int st=64; st>0; st>>=1){ if (tid<st) s_red[tid]+=s_red[tid+st]; __syncthreads(); }
    if (tid == 0) g_sigma[bid] = s_red[0];
  } else {
    for (int t = (bid-3)*NTHR + tid; t < NA*FF; t += (NBLK-3)*NTHR) {
      int a = t >> 7, f = t & 127;
      int zi = z[a]; if (zi < 1) zi = 1; if (zi > 100) zi = 100;
      g_featA[t] = tanhf(emb[(zi-1)*FF+f]);
    }
    if (bid == 3) {
      for (int i = tid; i < NA; i += NTHR) g_cnt[i] = 0;
      if (tid < NB) {
        float c[9];
        #pragma unroll
        for (int k=0;k<9;k++) c[k] = cell[tid*9+k];
        float cx = c[4]*c[8] - c[5]*c[7];
        float cy = c[5]*c[6] - c[3]*c[8];
        float cz = c[3]*c[7] - c[4]*c[6];
        float vol = c[0]*cx + c[1]*cy + c[2]*cz;
        g_radius[tid] = cbrtf(fabsf(vol)/(float)NN);   // RADIUS_RATE = 1
      }
    }
  }
  grid.sync();

  // ================= S1: neighbor list (atom per block, strided) =================
  {
    const float PI = 3.14159265358979323846f;
    for (int i = bid; i < NA; i += NBLK) {
      int b = i / NN;
      float pix = pos[i*3+0], piy = pos[i*3+1], piz = pos[i*3+2];
      float rb  = g_radius[b];
      float rb2 = rb*rb;
      float cl[9];
      #pragma unroll
      for (int k=0;k<9;k++) cl[k] = cell[b*9+k];
      for (int cand = tid; cand < NN*CC; cand += NTHR) {
        int j = cand / CC, c = cand - j*CC;
        float gx = (float)(c/9) - 1.0f;
        float gy = (float)((c/3)%3) - 1.0f;
        float gz = (float)(c%3) - 1.0f;
        float ox = gx*cl[0] + gy*cl[3] + gz*cl[6];
        float oy = gx*cl[1] + gy*cl[4] + gz*cl[7];
        float oz = gx*cl[2] + gy*cl[5] + gz*cl[8];
        int jg = b*NN + j;
        float dx = pix - (pos[jg*3+0] + ox);
        float dy = piy - (pos[jg*3+1] + oy);
        float dz = piz - (pos[jg*3+2] + oz);
        float d2 = dx*dx + dy*dy + dz*dz;
        if (d2 <= rb2 && d2 > 1e-4f) {
          float dist = sqrtf(fmaxf(d2, 1e-12f));
          float w = cosf(dist*PI/rb) + 1.0f;
          int slot = atomicAdd(&g_cnt[i], 1);
          if (slot < MAXNBR) {
            g_nj[i*MAXNBR+slot] = jg;
            g_nd[i*MAXNBR+slot] = dist;
            g_nw[i*MAXNBR+slot] = w;
          }
        }
      }
    }
  }
  grid.sync();

  // ================= conv layers =================
  const int h = tid >> 7, f = tid & 127;   // two concurrent 128-wide lanes per block
  for (int l = 0; l < 3; l++) {
    const float* fin  = (l & 1) ? g_featB : g_featA;
    float*       fout = (l & 1) ? g_featA : g_featB;
    const float* Wfb = conv_Wf + l*3*FF*FF;
    const float* Wsb = conv_Ws + l*3*FF*FF;

    // ---- proj: 1536 (atom,which) matvec tasks; 6 per block, 2 at a time ----
    for (int round = 0; round < 3; round++) {
      int task = bid*6 + round*2 + h;          // exactly covers 0..1535
      int i = task >> 2, which = task & 3;
      const float* W = (which==0) ? Wfb
                     : (which==1) ? (Wfb + FF*FF)
                     : (which==2) ? Wsb
                     :              (Wsb + FF*FF);
      __syncthreads();
      s_ft[h][f] = fin[i*FF+f];
      __syncthreads();
      float s = 0.f;
      #pragma unroll 8
      for (int k=0;k<FF;k++) s += s_ft[h][k]*W[k*FF+f];
      g_proj[(i*4+which)*FF+f] = s;
    }
    grid.sync();

    // ---- edge + post: block-half per atom, register accumulate (no atomics) ----
    {
      int i = bid + (h << 8);                  // atoms bid and bid+256
      if (i < NA) {
        float gi  = g_proj[(i*4+0)*FF+f];
        float si  = g_proj[(i*4+2)*FF+f];
        float bff = conv_bf[l*FF+f];
        float bsf = conv_bs[l*FF+f];
        const float* Wf2 = Wfb + 2*FF*FF;
        const float* Ws2 = Wsb + 2*FF*FF;
        const float step  = 6.0f/127.0f;
        const float coeff = -0.5f/(step*step);
        float msg = 0.f;
        int n = g_cnt[i]; if (n > MAXNBR) n = MAXNBR;
        for (int e=0;e<n;e++) {
          int   jg   = g_nj[i*MAXNBR+e];
          float dist = g_nd[i*MAXNBR+e];
          float w    = g_nw[i*MAXNBR+e];
          // Gaussian band: terms beyond |dist - k*step| > 9*step are < 2e-18 (exact in fp32)
          float center = dist / step;
          int kmin = (int)ceilf(center - 9.0f);  if (kmin < 0)   kmin = 0;
          int kmax = (int)floorf(center + 9.0f); if (kmax > 127) kmax = 127;
          float ge = 0.f, se = 0.f;
          for (int k = kmin; k <= kmax; k++) {
            float dd = dist - step*(float)k;
            float a  = expf(coeff*dd*dd);
            ge += a * Wf2[k*FF+f];
            se += a * Ws2[k*FF+f];
          }
          float g = sigmoidf(gi + g_proj[(jg*4+1)*FF+f] + ge + bff);
          float s = softplusf(si + g_proj[(jg*4+3)*FF+f] + se + bsf);
          msg += g*s*w;
        }
        fout[i*FF+f] = softplusf(fin[i*FF+f] + msg);
      }
    }
    grid.sync();
  }

  // ================= mean over atoms + FC chain + head (blocks 0-15) =================
  if (bid < NB) {
    if (tid < FF) {
      float s0 = 0.f;
      for (int n=0;n<NN;n++) s0 += g_featB[(bid*NN+n)*FF+tid];  // featB = layer-3 output
      s_u[tid] = s0/(float)NN;
    }
    __syncthreads();
    for (int l=0;l<3;l++) {
      float inv_s = 1.0f/g_sigma[l];
      if (tid < FF) {
        float s = 0.f;
        #pragma unroll 8
        for (int k=0;k<FF;k++) s += s_u[k]*fc_W[l*FF*FF + k*FF+tid];
        s_v[tid] = softplusf(s*inv_s + fc_b[l*FF+tid]);
      }
      __syncthreads();
      if (tid < FF) s_u[tid] = s_v[tid];
      __syncthreads();
    }
    if (tid < FF) s_red[tid] = s_u[tid]*W_out[tid];
    __syncthreads();
    for (int st=64; st>0; st>>=1){ if (tid<st) s_red[tid]+=s_red[tid+st]; __syncthreads(); }
    if (tid==0) out[bid] = s_red[0] + b_out[0];
  }
}

extern "C" void kernel_launch(void* const* d_in, const int* in_sizes, int n_in,
                              void* d_out, int out_size, void* d_ws, size_t ws_size,
                              hipStream_t stream) {
  const float* pos     = (const float*)d_in[0];
  const float* cell    = (const float*)d_in[1];
  const float* emb     = (const float*)d_in[2];
  const float* conv_Wf = (const float*)d_in[3];
  const float* conv_bf = (const float*)d_in[4];
  const float* conv_Ws = (const float*)d_in[5];
  const float* conv_bs = (const float*)d_in[6];
  const float* fc_W    = (const float*)d_in[7];
  const float* fc_b    = (const float*)d_in[8];
  const float* W_out   = (const float*)d_in[9];
  const float* b_out   = (const float*)d_in[10];
  const int*   z       = (const int*)d_in[11];
  float*       out     = (float*)d_out;
  // d_in[12] = batch (unused); d_ws unused (static device scratch)
  // All tensors fp32 (validated R3/R4: absmax == 0.0 vs np reference)

  void* args[] = { (void*)&pos, (void*)&cell, (void*)&emb,
                   (void*)&conv_Wf, (void*)&conv_bf, (void*)&conv_Ws, (void*)&conv_bs,
                   (void*)&fc_W, (void*)&fc_b, (void*)&W_out, (void*)&b_out,
                   (void*)&z, (void*)&out };
  hipLaunchCooperativeKernel((void*)k_mega, dim3(NBLK), dim3(NTHR), args, 0, stream);
}

// Round 6
// 262.404 us; speedup vs baseline: 1.7866x; 1.7866x over previous
//
#include <hip/hip_runtime.h>
#include <math.h>

#define NB 16
#define NN 24
#define NA 384       /* atoms total */
#define FF 128
#define CC 27
#define MAXNBR 32    /* physically <= 23 possible (image spacing L > 2r) */

// ---- static device scratch (d_ws unused; everything read is rewritten every call) ----
__device__ int   g_cnt[NA];
__device__ float g_sigma[4];
__device__ int   g_nj[NA*MAXNBR];
__device__ float g_nd[NA*MAXNBR];
__device__ float g_nw[NA*MAXNBR];
__device__ float g_featA[NA*FF];
__device__ float g_featB[NA*FF];

__device__ __forceinline__ float softplusf(float x){ return fmaxf(x,0.f) + log1pf(expf(-fabsf(x))); }
__device__ __forceinline__ float sigmoidf(float x){ return 1.f/(1.f+expf(-x)); }

// ============ K1: sigma (blocks 0-2) | per-atom feat0 + neighbor list (blocks 3+) ============
__global__ void __launch_bounds__(256)
k_prep(const float* __restrict__ pos, const float* __restrict__ cell,
       const float* __restrict__ emb, const float* __restrict__ fc_W,
       const int* __restrict__ z)
{
  const int bid = blockIdx.x, tid = threadIdx.x;
  __shared__ float s_w[FF*129];               // sigma only; stride 129 = conflict-free
  __shared__ float s_u[FF], s_v[FF], s_red[FF];
  __shared__ float s_cell[9];
  __shared__ float s_rb;
  __shared__ int   s_cnt;

  if (bid < 3) {
    // ---- spectral-norm power iteration (5 iters, eps=1e-12), W cached in LDS ----
    const float* W = fc_W + bid*FF*FF;
    for (int idx = tid; idx < FF*FF; idx += 256) {
      s_w[(idx >> 7)*129 + (idx & 127)] = W[idx];   // coalesced
    }
    if (tid < FF) s_u[tid] = 0.08838834764831845f;  // 1/sqrt(128)
    __syncthreads();
    for (int it = 0; it < 5; it++) {
      if (tid < FF) {                               // v = W u
        float s = 0.f;
        #pragma unroll 8
        for (int c=0;c<FF;c++) s += s_w[tid*129+c]*s_u[c];
        s_v[tid] = s; s_red[tid] = s*s;
      }
      __syncthreads();
      for (int st=64; st>0; st>>=1){ if (tid<st) s_red[tid]+=s_red[tid+st]; __syncthreads(); }
      float nv = sqrtf(s_red[0]) + 1e-12f;
      __syncthreads();
      if (tid < FF) s_v[tid] /= nv;
      __syncthreads();
      if (tid < FF) {                               // u = W^T v
        float s = 0.f;
        #pragma unroll 8
        for (int r=0;r<FF;r++) s += s_w[r*129+tid]*s_v[r];
        s_u[tid] = s; s_red[tid] = s*s;
      }
      __syncthreads();
      for (int st=64; st>0; st>>=1){ if (tid<st) s_red[tid]+=s_red[tid+st]; __syncthreads(); }
      float nu = sqrtf(s_red[0]) + 1e-12f;
      __syncthreads();
      if (tid < FF) s_u[tid] /= nu;
      __syncthreads();
    }
    if (tid < FF) {                                 // sigma = v . (W u)
      float s = 0.f;
      #pragma unroll 8
      for (int c=0;c<FF;c++) s += s_w[tid*129+c]*s_u[c];
      s_red[tid] = s_v[tid]*s;
    }
    __syncthreads();
    for (int st=64; st>0; st>>=1){ if (tid<st) s_red[tid]+=s_red[tid+st]; __syncthreads(); }
    if (tid == 0) g_sigma[bid] = s_red[0];
  } else {
    // ---- one atom per block ----
    const int i = bid - 3;
    const int b = i / NN;
    if (tid < FF) {
      int zi = z[i]; if (zi < 1) zi = 1; if (zi > 100) zi = 100;
      g_featA[i*FF+tid] = tanhf(emb[(zi-1)*FF+tid]);
    }
    if (tid < 9) s_cell[tid] = cell[b*9+tid];
    if (tid == 0) s_cnt = 0;
    __syncthreads();
    if (tid == 0) {
      const float* c = s_cell;
      float cx = c[4]*c[8] - c[5]*c[7];
      float cy = c[5]*c[6] - c[3]*c[8];
      float cz = c[3]*c[7] - c[4]*c[6];
      float vol = c[0]*cx + c[1]*cy + c[2]*cz;
      s_rb = cbrtf(fabsf(vol)/(float)NN);           // RADIUS_RATE = 1
    }
    __syncthreads();
    const float rb = s_rb, rb2 = rb*rb;
    const float pix = pos[i*3+0], piy = pos[i*3+1], piz = pos[i*3+2];
    const float PI = 3.14159265358979323846f;
    for (int cand = tid; cand < NN*CC; cand += 256) {
      int j = cand / CC, c = cand - j*CC;
      float gx = (float)(c/9) - 1.0f;
      float gy = (float)((c/3)%3) - 1.0f;
      float gz = (float)(c%3) - 1.0f;
      float ox = gx*s_cell[0] + gy*s_cell[3] + gz*s_cell[6];
      float oy = gx*s_cell[1] + gy*s_cell[4] + gz*s_cell[7];
      float oz = gx*s_cell[2] + gy*s_cell[5] + gz*s_cell[8];
      int jg = b*NN + j;
      float dx = pix - (pos[jg*3+0] + ox);
      float dy = piy - (pos[jg*3+1] + oy);
      float dz = piz - (pos[jg*3+2] + oz);
      float d2 = dx*dx + dy*dy + dz*dz;
      if (d2 <= rb2 && d2 > 1e-4f) {
        float dist = sqrtf(fmaxf(d2, 1e-12f));
        float w = cosf(dist*PI/rb) + 1.0f;
        int slot = atomicAdd(&s_cnt, 1);            // block-local, cheap
        if (slot < MAXNBR) {
          g_nj[i*MAXNBR+slot] = jg;
          g_nd[i*MAXNBR+slot] = dist;
          g_nw[i*MAXNBR+slot] = w;
        }
      }
    }
    __syncthreads();
    if (tid == 0) g_cnt[i] = (s_cnt > MAXNBR) ? MAXNBR : s_cnt;
  }
}

// ============ K2-K4: one conv layer, block per atom, redundant neighbor projections ========
__global__ void __launch_bounds__(256)
k_layer(int layer,
        const float* __restrict__ conv_Wf, const float* __restrict__ conv_bf,
        const float* __restrict__ conv_Ws, const float* __restrict__ conv_bs)
{
  const int i = blockIdx.x;                    // atom
  const int tid = threadIdx.x;
  const int h = tid >> 7, f = tid & 127;       // half-index, feature
  const float* fin  = (layer & 1) ? g_featB : g_featA;
  float*       fout = (layer & 1) ? g_featA : g_featB;
  const float* Wfb = conv_Wf + layer*3*FF*FF;  // Wf[:F]
  const float* Wsb = conv_Ws + layer*3*FF*FF;  // Ws[:F]
  const float* Wf1 = Wfb + FF*FF;              // Wf[F:2F]
  const float* Ws1 = Wsb + FF*FF;
  const float* Wf2 = Wfb + 2*FF*FF;            // Wf[2F:]
  const float* Ws2 = Wsb + 2*FF*FF;

  __shared__ float fti[FF], ftj[FF];
  __shared__ float part[2][2][FF];             // [g|s][half][f]
  __shared__ float sg[FF], ss[FF], msg[FF];

  if (tid < FF) { fti[tid] = fin[i*FF+tid]; msg[tid] = 0.f; }
  __syncthreads();

  // gi/si: k-loop split across halves
  {
    float pg = 0.f, ps = 0.f;
    const int k0 = h*64;
    #pragma unroll 8
    for (int k = k0; k < k0+64; k++) {
      float a = fti[k];
      pg += a * Wfb[k*FF+f];
      ps += a * Wsb[k*FF+f];
    }
    part[0][h][f] = pg; part[1][h][f] = ps;
  }
  __syncthreads();
  const float gi  = part[0][0][f] + part[0][1][f];
  const float si  = part[1][0][f] + part[1][1][f];
  const float bff = conv_bf[layer*FF+f];
  const float bsf = conv_bs[layer*FF+f];
  const float step  = 6.0f/127.0f;
  const float coeff = -0.5f/(step*step);

  const int n = g_cnt[i];
  for (int e = 0; e < n; e++) {
    const int   jg   = g_nj[i*MAXNBR+e];
    const float dist = g_nd[i*MAXNBR+e];
    const float w    = g_nw[i*MAXNBR+e];
    __syncthreads();                           // (A) prev-iter consumers done
    if (tid < FF) ftj[tid] = fin[jg*FF+tid];
    __syncthreads();                           // (B)
    float pg = 0.f, ps = 0.f;
    const int k0 = h*64;
    #pragma unroll 8
    for (int k = k0; k < k0+64; k++) {
      float a = ftj[k];
      pg += a * Wf1[k*FF+f];
      ps += a * Ws1[k*FF+f];
    }
    part[0][h][f] = pg; part[1][h][f] = ps;
    __syncthreads();                           // (C)
    // banded Gaussian: |dist-k*step|>9*step terms < 2e-18 (exact in fp32; validated R4/R5)
    float center = dist / step;
    int kmin = (int)ceilf(center - 9.0f);  if (kmin < 0)   kmin = 0;
    int kmax = (int)floorf(center + 9.0f); if (kmax > 127) kmax = 127;
    const float* W2 = h ? Ws2 : Wf2;
    float ee = 0.f;
    for (int k = kmin; k <= kmax; k++) {
      float dd = dist - step*(float)k;
      ee += expf(coeff*dd*dd) * W2[k*FF+f];
    }
    if (h == 0) {
      float gj = part[0][0][f] + part[0][1][f];
      sg[f] = sigmoidf(gi + gj + ee + bff);
    } else {
      float sj = part[1][0][f] + part[1][1][f];
      ss[f] = softplusf(si + sj + ee + bsf);
    }
    __syncthreads();                           // (D)
    if (tid < FF) msg[f] += sg[f]*ss[f]*w;
  }
  __syncthreads();
  if (tid < FF) fout[i*FF+f] = softplusf(fti[f] + msg[f]);
}

// ============ K5: mean over atoms + spectral-normed FC chain + head ============
__global__ void __launch_bounds__(128)
k_final(const float* __restrict__ fc_W, const float* __restrict__ fc_b,
        const float* __restrict__ W_out, const float* __restrict__ b_out,
        float* __restrict__ out)
{
  const int b = blockIdx.x, f = threadIdx.x;
  __shared__ float hh[FF], tmp[FF], red[FF];
  float s0 = 0.f;
  for (int n=0;n<NN;n++) s0 += g_featB[(b*NN+n)*FF+f];   // after 3 layers: A->B->A->B
  hh[f] = s0/(float)NN;
  __syncthreads();
  for (int l=0;l<3;l++) {
    float inv_s = 1.0f/g_sigma[l];
    float s = 0.f;
    #pragma unroll 8
    for (int k=0;k<FF;k++) s += hh[k]*fc_W[l*FF*FF + k*FF+f];
    tmp[f] = softplusf(s*inv_s + fc_b[l*FF+f]);
    __syncthreads();
    hh[f] = tmp[f];
    __syncthreads();
  }
  red[f] = hh[f]*W_out[f];
  __syncthreads();
  for (int st=64; st>0; st>>=1){ if (f<st) red[f]+=red[f+st]; __syncthreads(); }
  if (f==0) out[b] = red[0] + b_out[0];
}

extern "C" void kernel_launch(void* const* d_in, const int* in_sizes, int n_in,
                              void* d_out, int out_size, void* d_ws, size_t ws_size,
                              hipStream_t stream) {
  const float* pos     = (const float*)d_in[0];
  const float* cell    = (const float*)d_in[1];
  const float* emb     = (const float*)d_in[2];
  const float* conv_Wf = (const float*)d_in[3];
  const float* conv_bf = (const float*)d_in[4];
  const float* conv_Ws = (const float*)d_in[5];
  const float* conv_bs = (const float*)d_in[6];
  const float* fc_W    = (const float*)d_in[7];
  const float* fc_b    = (const float*)d_in[8];
  const float* W_out   = (const float*)d_in[9];
  const float* b_out   = (const float*)d_in[10];
  const int*   z       = (const int*)d_in[11];
  // d_in[12] = batch (unused); d_ws unused (static device scratch)
  // All tensors fp32 (validated R3-R5: absmax == 0.0 vs np reference)

  k_prep<<<NA+3, 256, 0, stream>>>(pos, cell, emb, fc_W, z);
  for (int l = 0; l < 3; l++)
    k_layer<<<NA, 256, 0, stream>>>(l, conv_Wf, conv_bf, conv_Ws, conv_bs);
  k_final<<<NB, 128, 0, stream>>>(fc_W, fc_b, W_out, b_out, (float*)d_out);
}

// Round 7
// 153.532 us; speedup vs baseline: 3.0536x; 1.7091x over previous
//
#include <hip/hip_runtime.h>
#include <math.h>

#define NB 16
#define NN 24
#define NA 384       /* atoms total */
#define FF 128
#define CC 27
#define MAXNBR 32    /* physically <= 23 possible (image spacing L > 2r) */

// ---- static device scratch (d_ws unused; everything read is rewritten every call) ----
__device__ int   g_cnt[NA];
__device__ float g_sigma[4];
__device__ int   g_nj[NA*MAXNBR];
__device__ float g_nd[NA*MAXNBR];
__device__ float g_nw[NA*MAXNBR];
__device__ float g_featA[NA*FF];
__device__ float g_featB[NA*FF];
__device__ float g_proj[NA*4*FF];   // per atom: gi, gj, si, sj of current layer

__device__ __forceinline__ float softplusf(float x){ return fmaxf(x,0.f) + log1pf(expf(-fabsf(x))); }
__device__ __forceinline__ float sigmoidf(float x){ return 1.f/(1.f+expf(-x)); }

// ============ K1: sigma (blocks 0-2) | per-atom feat0 + nbr list + proj layer0 (blocks 3+) ====
__global__ void __launch_bounds__(512)
k_prep(const float* __restrict__ pos, const float* __restrict__ cell,
       const float* __restrict__ emb, const float* __restrict__ fc_W,
       const float* __restrict__ conv_Wf, const float* __restrict__ conv_Ws,
       const int* __restrict__ z)
{
  const int bid = blockIdx.x, tid = threadIdx.x;
  const int q = tid >> 7, f = tid & 127;

  if (bid < 3) {
    // ---- spectral-norm power iteration (5 iters, eps=1e-12), W in LDS stride 129 ----
    __shared__ float s_w[FF*129];
    __shared__ float s_u[FF], s_v[FF], s_red[FF];
    __shared__ float s_part[4][FF];
    const float* W = fc_W + bid*FF*FF;
    for (int idx = tid; idx < FF*FF; idx += 512)
      s_w[(idx >> 7)*129 + (idx & 127)] = W[idx];          // coalesced
    if (tid < FF) s_u[tid] = 0.08838834764831845f;         // 1/sqrt(128)
    __syncthreads();
    for (int it = 0; it < 5; it++) {
      { // v = W u  (k-split over quarters)
        float p = 0.f;
        #pragma unroll
        for (int k = q*32; k < q*32+32; k++) p += s_w[f*129+k]*s_u[k];
        s_part[q][f] = p;
      }
      __syncthreads();
      if (tid < FF) { float s = s_part[0][f]+s_part[1][f]+s_part[2][f]+s_part[3][f];
                      s_v[f] = s; s_red[f] = s*s; }
      __syncthreads();
      for (int st=64; st>0; st>>=1){ if (tid<st) s_red[tid]+=s_red[tid+st]; __syncthreads(); }
      float nv = sqrtf(s_red[0]) + 1e-12f;
      __syncthreads();
      if (tid < FF) s_v[f] /= nv;
      __syncthreads();
      { // u = W^T v  (r-split over quarters)
        float p = 0.f;
        #pragma unroll
        for (int r = q*32; r < q*32+32; r++) p += s_w[r*129+f]*s_v[r];
        s_part[q][f] = p;
      }
      __syncthreads();
      if (tid < FF) { float s = s_part[0][f]+s_part[1][f]+s_part[2][f]+s_part[3][f];
                      s_u[f] = s; s_red[f] = s*s; }
      __syncthreads();
      for (int st=64; st>0; st>>=1){ if (tid<st) s_red[tid]+=s_red[tid+st]; __syncthreads(); }
      float nu = sqrtf(s_red[0]) + 1e-12f;
      __syncthreads();
      if (tid < FF) s_u[f] /= nu;
      __syncthreads();
    }
    { // sigma = v . (W u)
      float p = 0.f;
      #pragma unroll
      for (int k = q*32; k < q*32+32; k++) p += s_w[f*129+k]*s_u[k];
      s_part[q][f] = p;
    }
    __syncthreads();
    if (tid < FF) s_red[f] = s_v[f]*(s_part[0][f]+s_part[1][f]+s_part[2][f]+s_part[3][f]);
    __syncthreads();
    for (int st=64; st>0; st>>=1){ if (tid<st) s_red[tid]+=s_red[tid+st]; __syncthreads(); }
    if (tid == 0) g_sigma[bid] = s_red[0];
  } else {
    // ---- one atom per block: feat0, radius, neighbor list, then proj layer 0 ----
    const int i = bid - 3;
    const int b = i / NN;
    __shared__ float ft[FF];
    __shared__ float s_cell[9];
    __shared__ float s_rb;
    __shared__ int   s_cnt;
    if (tid < FF) {
      int zi = z[i]; if (zi < 1) zi = 1; if (zi > 100) zi = 100;
      float v = tanhf(emb[(zi-1)*FF+tid]);
      ft[tid] = v;
      g_featA[i*FF+tid] = v;
    }
    if (tid >= 256 && tid < 265) s_cell[tid-256] = cell[b*9 + tid - 256];
    if (tid == 500) s_cnt = 0;
    __syncthreads();
    if (tid == 0) {
      const float* c = s_cell;
      float cx = c[4]*c[8] - c[5]*c[7];
      float cy = c[5]*c[6] - c[3]*c[8];
      float cz = c[3]*c[7] - c[4]*c[6];
      float vol = c[0]*cx + c[1]*cy + c[2]*cz;
      s_rb = cbrtf(fabsf(vol)/(float)NN);               // RADIUS_RATE = 1
    }
    __syncthreads();
    const float rb = s_rb, rb2 = rb*rb;
    const float pix = pos[i*3+0], piy = pos[i*3+1], piz = pos[i*3+2];
    const float PI = 3.14159265358979323846f;
    for (int cand = tid; cand < NN*CC; cand += 512) {
      int j = cand / CC, c = cand - j*CC;
      float gx = (float)(c/9) - 1.0f;
      float gy = (float)((c/3)%3) - 1.0f;
      float gz = (float)(c%3) - 1.0f;
      float ox = gx*s_cell[0] + gy*s_cell[3] + gz*s_cell[6];
      float oy = gx*s_cell[1] + gy*s_cell[4] + gz*s_cell[7];
      float oz = gx*s_cell[2] + gy*s_cell[5] + gz*s_cell[8];
      int jg = b*NN + j;
      float dx = pix - (pos[jg*3+0] + ox);
      float dy = piy - (pos[jg*3+1] + oy);
      float dz = piz - (pos[jg*3+2] + oz);
      float d2 = dx*dx + dy*dy + dz*dz;
      if (d2 <= rb2 && d2 > 1e-4f) {
        float dist = sqrtf(fmaxf(d2, 1e-12f));
        float w = cosf(dist*PI/rb) + 1.0f;
        int slot = atomicAdd(&s_cnt, 1);                // block-local
        if (slot < MAXNBR) {
          g_nj[i*MAXNBR+slot] = jg;
          g_nd[i*MAXNBR+slot] = dist;
          g_nw[i*MAXNBR+slot] = w;
        }
      }
    }
    __syncthreads();
    if (tid == 0) g_cnt[i] = (s_cnt > MAXNBR) ? MAXNBR : s_cnt;
    // ---- proj layer 0: quarter q computes one of {gi,gj,si,sj} from ft ----
    const float* W = (q==0) ? conv_Wf
                   : (q==1) ? (conv_Wf + FF*FF)
                   : (q==2) ? conv_Ws
                   :          (conv_Ws + FF*FF);
    float s = 0.f;
    #pragma unroll 8
    for (int k=0;k<FF;k++) s += ft[k]*W[k*FF+f];
    g_proj[(i*4+q)*FF+f] = s;
  }
}

// ============ K2-K4: edges of layer l (+ fused proj of layer l+1) ============
__global__ void __launch_bounds__(512)
k_edge(int layer, int do_proj,
       const float* __restrict__ conv_Wf, const float* __restrict__ conv_bf,
       const float* __restrict__ conv_Ws, const float* __restrict__ conv_bs)
{
  const int i = blockIdx.x, tid = threadIdx.x;
  const int q = tid >> 7, f = tid & 127;
  const float* fin  = (layer & 1) ? g_featB : g_featA;
  float*       fout = (layer & 1) ? g_featA : g_featB;
  const float* Wf2 = conv_Wf + layer*3*FF*FF + 2*FF*FF;   // Wf[2F:]
  const float* Ws2 = conv_Ws + layer*3*FF*FF + 2*FF*FF;   // Ws[2F:]

  const float gi  = g_proj[(i*4+0)*FF+f];
  const float si  = g_proj[(i*4+2)*FF+f];
  const float bff = conv_bf[layer*FF+f];
  const float bsf = conv_bs[layer*FF+f];
  const float step  = 6.0f/127.0f;
  const float coeff = -0.5f/(step*step);
  const int n = g_cnt[i];

  // quarter q processes edges q, q+4, ... ; no barriers inside the loop
  float msg = 0.f;
  for (int e = q; e < n; e += 4) {
    const int   jg   = g_nj[i*MAXNBR+e];
    const float dist = g_nd[i*MAXNBR+e];
    const float w    = g_nw[i*MAXNBR+e];
    const float gj   = g_proj[(jg*4+1)*FF+f];
    const float sj   = g_proj[(jg*4+3)*FF+f];
    // banded Gaussian: |dist-k*step|>9*step terms < 2e-18 (exact in fp32; validated R4-R6)
    float center = dist / step;
    int kmin = (int)ceilf(center - 9.0f);  if (kmin < 0)   kmin = 0;
    int kmax = (int)floorf(center + 9.0f); if (kmax > 127) kmax = 127;
    float ge = 0.f, se = 0.f;
    for (int k = kmin; k <= kmax; k++) {
      float dd = dist - step*(float)k;
      float a  = expf(coeff*dd*dd);
      ge += a * Wf2[k*FF+f];
      se += a * Ws2[k*FF+f];
    }
    msg += sigmoidf(gi + gj + ge + bff) * softplusf(si + sj + se + bsf) * w;
  }

  __shared__ float sm[4][FF];
  __shared__ float fnew[FF];
  sm[q][f] = msg;
  __syncthreads();
  if (tid < FF) {
    float m = sm[0][f] + sm[1][f] + sm[2][f] + sm[3][f];
    float v = softplusf(fin[i*FF+f] + m);
    fnew[f] = v;
    fout[i*FF+f] = v;
  }
  if (do_proj) {
    __syncthreads();
    const float* WfbN = conv_Wf + (layer+1)*3*FF*FF;
    const float* WsbN = conv_Ws + (layer+1)*3*FF*FF;
    const float* W = (q==0) ? WfbN
                   : (q==1) ? (WfbN + FF*FF)
                   : (q==2) ? WsbN
                   :          (WsbN + FF*FF);
    float s = 0.f;
    #pragma unroll 8
    for (int k=0;k<FF;k++) s += fnew[k]*W[k*FF+f];
    g_proj[(i*4+q)*FF+f] = s;
  }
}

// ============ K5: mean over atoms + spectral-normed FC chain + head ============
__global__ void __launch_bounds__(128)
k_final(const float* __restrict__ fc_W, const float* __restrict__ fc_b,
        const float* __restrict__ W_out, const float* __restrict__ b_out,
        float* __restrict__ out)
{
  const int b = blockIdx.x, f = threadIdx.x;
  __shared__ float hh[FF], tmp[FF], red[FF];
  float s0 = 0.f;
  for (int n=0;n<NN;n++) s0 += g_featB[(b*NN+n)*FF+f];   // A->B->A->B after 3 layers
  hh[f] = s0/(float)NN;
  __syncthreads();
  for (int l=0;l<3;l++) {
    float inv_s = 1.0f/g_sigma[l];
    float s = 0.f;
    #pragma unroll 8
    for (int k=0;k<FF;k++) s += hh[k]*fc_W[l*FF*FF + k*FF+f];
    tmp[f] = softplusf(s*inv_s + fc_b[l*FF+f]);
    __syncthreads();
    hh[f] = tmp[f];
    __syncthreads();
  }
  red[f] = hh[f]*W_out[f];
  __syncthreads();
  for (int st=64; st>0; st>>=1){ if (f<st) red[f]+=red[f+st]; __syncthreads(); }
  if (f==0) out[b] = red[0] + b_out[0];
}

extern "C" void kernel_launch(void* const* d_in, const int* in_sizes, int n_in,
                              void* d_out, int out_size, void* d_ws, size_t ws_size,
                              hipStream_t stream) {
  const float* pos     = (const float*)d_in[0];
  const float* cell    = (const float*)d_in[1];
  const float* emb     = (const float*)d_in[2];
  const float* conv_Wf = (const float*)d_in[3];
  const float* conv_bf = (const float*)d_in[4];
  const float* conv_Ws = (const float*)d_in[5];
  const float* conv_bs = (const float*)d_in[6];
  const float* fc_W    = (const float*)d_in[7];
  const float* fc_b    = (const float*)d_in[8];
  const float* W_out   = (const float*)d_in[9];
  const float* b_out   = (const float*)d_in[10];
  const int*   z       = (const int*)d_in[11];
  // d_in[12] = batch (unused); d_ws unused (static device scratch)
  // All tensors fp32 (validated R3-R6: absmax == 0.0 vs np reference)

  k_prep<<<NA+3, 512, 0, stream>>>(pos, cell, emb, fc_W, conv_Wf, conv_Ws, z);
  k_edge<<<NA, 512, 0, stream>>>(0, 1, conv_Wf, conv_bf, conv_Ws, conv_bs);
  k_edge<<<NA, 512, 0, stream>>>(1, 1, conv_Wf, conv_bf, conv_Ws, conv_bs);
  k_edge<<<NA, 512, 0, stream>>>(2, 0, conv_Wf, conv_bf, conv_Ws, conv_bs);
  k_final<<<NB, 128, 0, stream>>>(fc_W, fc_b, W_out, b_out, (float*)d_out);
}